// Round 15
// baseline (360.815 us; speedup 1.0000x reference)
//
#include <hip/hip_runtime.h>

#define DEVFN __device__ __forceinline__

typedef float  f32x4  __attribute__((ext_vector_type(4)));
typedef short  bf16x8 __attribute__((ext_vector_type(8)));

// Problem constants
constexpr int ENC = 168;
constexpr int DEC = 24;
constexpr int BT  = 16;            // batch tile (MFMA N)
constexpr int NBLK = 4096 / BT;    // 256 blocks -> 1 per CU (256 thr, 1 wave/SIMD)

constexpr float LOG2E  = 1.4426950408889634f;
constexpr float LOG2E2 = 2.8853900817779268f;

// Workspace layout. ushort region: bf16 weight fragments [c][tt16][lane64][j8]
// K-maps: L0: k<20 x (c0), k==20 dup of col0 (lo-plane), k in[32,96) h0 (c1,c2)
//         L1: k<64 h0 (c1,c2), k in[64,128) h1 (c3,c4)
//         DEC: k<20 xin (c0), k==20 dup col0, k in[32,96) h1 (c3,c4)
constexpr int W0F = 0;             // 3*16*512 = 24576 ushorts
constexpr int W1F = 24576;         // 4*16*512 = 32768
constexpr int WDF = 57344;         // 3*16*512 = 24576
// float region (float indices; ushort total 81920 = 163840 B = 40960 floats)
constexpr int F_B0   = 40960;
constexpr int F_B1   = 41216;
constexpr int F_BD   = 41472;
constexpr int F_WOUT = 41728;
constexpr int F_BOUT = 41792;
constexpr int F_EMB  = 41793;      // [574] hour120 wd24 mo52 woy378
constexpr int NEMB = 574;

DEVFN ushort f2bf(float v) {       // fp32 -> bf16 bits, RNE (scalar path)
    unsigned b = __float_as_uint(v);
    return (ushort)((b + 0x7FFFu + ((b >> 16) & 1u)) >> 16);
}
DEVFN float bf2f(ushort u) { return __uint_as_float(((unsigned)u) << 16); }
DEVFN unsigned cvt_pk_bf16(float a, float b) {  // hw packed RNE
    unsigned r;
    asm("v_cvt_pk_bf16_f32 %0, %1, %2" : "=v"(r) : "v"(a), "v"(b));
    return r;
}
DEVFN float exp2n(float x) {       // 2^(-x), neg as free input modifier
    float r;
    asm("v_exp_f32 %0, -%1" : "=v"(r) : "v"(x));
    return r;
}
// pin a value into registers: asm consumes+redefines it -> no remat of the load
DEVFN void pinv(bf16x8& v) { asm volatile("" : "+v"(v)); }
DEVFN void pinf(f32x4& v)  { asm volatile("" : "+v"(v)); }

// LSTM cell on pre-scaled gates (i,f,o x log2e; g x 2log2e), fused-rcp pairs.
DEVFN float lstm_cell(float gi, float gf, float gg, float go, float& c) {
    float a  = exp2n(fmaxf(gi, -21.f));            // e^-i
    float b  = exp2n(fmaxf(gg, -43.f));            // e^-2g
    float f  = exp2n(gf);                          // e^-f
    float sf = __builtin_amdgcn_rcpf(1.f + f);
    float it = (1.f - b) * __builtin_amdgcn_rcpf(fmaf(a, b, a + b + 1.f));
    c = fmaf(sf, c, it);
    float d  = exp2n(fmaxf(c, -15.f) * LOG2E2);    // e^-2c
    float o  = exp2n(fmaxf(go, -21.f));            // e^-o
    return (1.f - d) * __builtin_amdgcn_rcpf(fmaf(o, d, o + d + 1.f));
}

// ---------------- prep: weights -> bf16 MFMA fragments (pre-scaled) --------
__global__ void prep_kernel(
    const float* __restrict__ w0ih, const float* __restrict__ w0hh,
    const float* __restrict__ b0ih, const float* __restrict__ b0hh,
    const float* __restrict__ w1ih, const float* __restrict__ w1hh,
    const float* __restrict__ b1ih, const float* __restrict__ b1hh,
    const float* __restrict__ wdih, const float* __restrict__ wdhh,
    const float* __restrict__ bdih, const float* __restrict__ bdhh,
    const float* __restrict__ wout, const float* __restrict__ boutp,
    const float* __restrict__ eh,   const float* __restrict__ ewd,
    const float* __restrict__ emo,  const float* __restrict__ ewoy,
    void* __restrict__ ws)
{
    ushort* wsu = (ushort*)ws;
    float*  wsf = (float*)ws;
    const int total = 81920 + 1407;
    for (int idx = blockIdx.x * blockDim.x + threadIdx.x; idx < total;
         idx += gridDim.x * blockDim.x) {
        if (idx < 81920) {
            int layer, q;
            if (idx < W1F)      { layer = 0; q = idx; }
            else if (idx < WDF) { layer = 1; q = idx - W1F; }
            else                { layer = 2; q = idx - WDF; }
            int c  = q >> 13;
            int tt = (q >> 9) & 15;
            int l  = (q >> 3) & 63;
            int j  = q & 7;
            int k  = c * 32 + (l >> 4) * 8 + j;
            int n  = tt * 16 + (l & 15);
            float v = 0.f;
            if (layer == 0) {
                if (k < 20) v = w0ih[n * 20 + k];
                else if (k == 20) v = w0ih[n * 20];            // lo-plane dup of col0
                else if (k >= 32 && k < 96) v = w0hh[n * 64 + (k - 32)];
            } else if (layer == 1) {
                if (k < 64) v = w1ih[n * 64 + k];
                else        v = w1hh[n * 64 + (k - 64)];
            } else {
                if (k < 20) v = wdih[n * 20 + k];
                else if (k == 20) v = wdih[n * 20];            // lo-plane dup of col0
                else if (k >= 32 && k < 96) v = wdhh[n * 64 + (k - 32)];
            }
            v *= ((n >> 6) == 2) ? LOG2E2 : LOG2E;   // pre-scale for exp2
            wsu[idx] = f2bf(v);
        } else {
            int f = idx - 81920;
            float v;
            if (f < 768) {
                float sc = (((f & 255) >> 6) == 2) ? LOG2E2 : LOG2E;
                if (f < 256)      v = (b0ih[f] + b0hh[f]) * sc;
                else if (f < 512) v = (b1ih[f - 256] + b1hh[f - 256]) * sc;
                else              v = (bdih[f - 512] + bdhh[f - 512]) * sc;
            }
            else if (f < 832) v = wout[f - 768];
            else if (f == 832) v = boutp[0];
            else {
                int e = f - 833;
                if (e < 120)      v = eh[e];
                else if (e < 144) v = ewd[e - 120];
                else if (e < 196) v = emo[e - 144];
                else              v = ewoy[e - 196];
            }
            wsf[40960 + f] = v;
        }
    }
}

DEVFN int offX(int k, int m) {     // chunk0 fragment offset, k in [0,32)
    return (m + 16 * (k >> 3)) * 8 + (k & 7);
}
// packed: 4 consecutive-k h values -> one b64 write
DEVFN void store_h4(ushort* A, int off, const float* h) {
    unsigned h01 = cvt_pk_bf16(h[0], h[1]);
    unsigned h23 = cvt_pk_bf16(h[2], h[3]);
    asm volatile("" : "+v"(h01), "+v"(h23));
    unsigned long long p = ((unsigned long long)h23 << 32) | h01;
    *(unsigned long long*)(A + off) = p;
}
// hi/lo pair for the k=0 feature (label/prev): hi at k=0, lo at k=20
DEVFN void store_prev(ushort* A, int m, float v) {
    ushort hi = f2bf(v);
    A[offX(0, m)]  = hi;
    A[offX(20, m)] = f2bf(v - bf2f(hi));
}

// ---------------- main persistent MFMA kernel: 256 thr, fused layers -------
// Wave w (0..3) owns units [16w,16w+16) of BOTH layers: per encoder iter it
// runs layer0(i) (12 MFMA) AND layer1(i-1) (16 MFMA) back-to-back in one
// stream, so the compiler interleaves MFMA-pipe and VALU-pipe work. Same
// barrier dataflow as the verified round-12 kernel (1 barrier/iter, dbuf).
__global__ __launch_bounds__(256)
__attribute__((amdgpu_waves_per_eu(1, 1)))
void lstm_mfma(
    const int* __restrict__ input_time, const float* __restrict__ label_p,
    const int* __restrict__ decoder_time, const void* __restrict__ ws,
    float* __restrict__ out)
{
    const ushort* wsu = (const ushort*)ws;
    const float*  wsf = (const float*)ws;

    // double-buffered activations: c0=x/xin, c1c2=h0, c3c4=h1 (bf16 frags)
    __shared__ __align__(16) ushort Abuf[2][5 * 512];
    __shared__ float s_emb[NEMB];
    __shared__ float s_wout[64];
    __shared__ float sh1[16 * 68];     // [m][u] padded
    __shared__ float s_bout;

    const int tid = threadIdx.x;
    const int w   = tid >> 6;          // wave 0..3
    const int l   = tid & 63;
    const int q   = l >> 4;
    const int m   = l & 15;
    const int b0g = blockIdx.x * BT;
    const int u0  = w * 16 + q * 4;    // this lane's 4 units (both layers)

    // h fragment store offsets: h0 -> c1c2, h1 -> c3c4
    const int hoff0 = (1 + (u0 >> 5)) * 512 +
                      (m + 16 * ((u0 & 31) >> 3)) * 8 + (u0 & 7);
    const int hoff1 = hoff0 + 1024;

    // ---- init ----
    for (int i = tid; i < 2 * 5 * 512; i += 256) ((ushort*)Abuf)[i] = 0;
    for (int i = tid; i < NEMB; i += 256) s_emb[i] = wsf[F_EMB + i];
    if (tid < 64) s_wout[tid] = wsf[F_WOUT + tid];
    if (tid == 0) s_bout = wsf[F_BOUT];

    // ---- weight fragments (A-operand, bf16), pinned register-resident ----
    bf16x8 wA0[3][4], wA1[4][4];       // [chunk][gamma]
#pragma unroll
    for (int c = 0; c < 3; c++)
#pragma unroll
        for (int g = 0; g < 4; g++) {
            wA0[c][g] = *(const bf16x8*)(wsu + W0F +
                (c * 16 + g * 4 + w) * 512 + l * 8);
            pinv(wA0[c][g]);
        }
#pragma unroll
    for (int c = 0; c < 4; c++)
#pragma unroll
        for (int g = 0; g < 4; g++) {
            wA1[c][g] = *(const bf16x8*)(wsu + W1F +
                (c * 16 + g * 4 + w) * 512 + l * 8);
            pinv(wA1[c][g]);
        }
    f32x4 bias0[4], bias1[4];
#pragma unroll
    for (int g = 0; g < 4; g++) {
        bias0[g] = *(const f32x4*)(wsf + F_B0 + g * 64 + u0);
        bias1[g] = *(const f32x4*)(wsf + F_B1 + g * 64 + u0);
        pinf(bias0[g]); pinf(bias1[g]);
    }

    float cst0[4] = {0.f, 0.f, 0.f, 0.f};
    float cst1[4] = {0.f, 0.f, 0.f, 0.f};

    // x-build roles: primary kk1 = tid>>4 (0..15); secondary kk2 = kk1+16
    // (16..19) for tid<64. batch = tid&15 = m.
    const int kk1 = tid >> 4;
    const int kk2 = kk1 + 16;
    const bool bx2 = (tid < 64);
    int sel1 = 0, estr1 = 0, ebase1 = 0;
    if (kk1 >= 1) {
        int f = kk1 - 1;
        if (f < 5)       { sel1 = 0; estr1 = 5; ebase1 = 0   + f; }
        else if (f < 8)  { sel1 = 1; estr1 = 3; ebase1 = 120 + (f - 5); }
        else if (f < 12) { sel1 = 2; estr1 = 4; ebase1 = 144 + (f - 8); }
        else             { sel1 = 3; estr1 = 7; ebase1 = 196 + (f - 12); }
    }
    const int ebase2 = 196 + (kk2 - 13);   // woy table, stride 7

    __syncthreads();
    {   // x(0) into Abuf[0]
        if (kk1 == 0) {
            store_prev(Abuf[0], m, label_p[(b0g + m) * ENC]);
        } else {
            int idx = input_time[((b0g + m) * ENC) * 4 + sel1];
            Abuf[0][offX(kk1, m)] = f2bf(s_emb[ebase1 + idx * estr1]);
        }
        if (bx2) {
            int idx2 = input_time[((b0g + m) * ENC) * 4 + 3];
            Abuf[0][offX(kk2, m)] = f2bf(s_emb[ebase2 + idx2 * 7]);
        }
    }
    __syncthreads();

    // ============ encoder: fused iter i = layer0(i) + layer1(i-1) ===========
    for (int i = 0; i <= ENC; ++i) {
        const ushort* Ar = Abuf[i & 1];
        ushort* Aw = Abuf[(i + 1) & 1];
        const bool L0 = (i < ENC), L1 = (i >= 1);

        // global prefetch for next x (overlaps LDS reads below)
        float pre_f = 0.f; int pre_i1 = 0, pre_i2 = 0;
        const bool encX  = (i + 1 < ENC);
        const bool decX0 = (i == ENC);
        if (encX) {
            if (kk1 == 0) pre_f  = label_p[(b0g + m) * ENC + (i + 1)];
            else          pre_i1 = input_time[((b0g + m) * ENC + (i + 1)) * 4 + sel1];
            if (bx2)      pre_i2 = input_time[((b0g + m) * ENC + (i + 1)) * 4 + 3];
        } else if (decX0) {
            if (kk1 == 0) pre_f  = label_p[(b0g + m) * ENC + (ENC - 1)];
            else          pre_i1 = decoder_time[((b0g + m) * DEC) * 4 + sel1];
            if (bx2)      pre_i2 = decoder_time[((b0g + m) * DEC) * 4 + 3];
        }

        // shared activation loads: a[0..2] feed L0, a[1..4] feed L1
        bf16x8 a[5];
#pragma unroll
        for (int c = 0; c < 5; c++)
            a[c] = *(const bf16x8*)(Ar + c * 512 + l * 8);

        f32x4 acc0[4], acc1[4];
        if (L0) {
#pragma unroll
            for (int g = 0; g < 4; g++)
                acc0[g] = __builtin_amdgcn_mfma_f32_16x16x32_bf16(
                    wA0[0][g], a[0], bias0[g], 0, 0, 0);
#pragma unroll
            for (int c = 1; c < 3; c++)
#pragma unroll
                for (int g = 0; g < 4; g++)
                    acc0[g] = __builtin_amdgcn_mfma_f32_16x16x32_bf16(
                        wA0[c][g], a[c], acc0[g], 0, 0, 0);
        }
        if (L1) {
#pragma unroll
            for (int g = 0; g < 4; g++)
                acc1[g] = __builtin_amdgcn_mfma_f32_16x16x32_bf16(
                    wA1[0][g], a[1], bias1[g], 0, 0, 0);
#pragma unroll
            for (int c = 1; c < 4; c++)
#pragma unroll
                for (int g = 0; g < 4; g++)
                    acc1[g] = __builtin_amdgcn_mfma_f32_16x16x32_bf16(
                        wA1[c][g], a[1 + c], acc1[g], 0, 0, 0);
        }
        if (L0) {
            float hv[4];
#pragma unroll
            for (int r = 0; r < 4; r++)
                hv[r] = lstm_cell(acc0[0][r], acc0[1][r], acc0[2][r], acc0[3][r], cst0[r]);
            store_h4(Aw, hoff0, hv);               // h0(i) -> c1c2
        }
        if (L1) {
            float hv[4];
#pragma unroll
            for (int r = 0; r < 4; r++)
                hv[r] = lstm_cell(acc1[0][r], acc1[1][r], acc1[2][r], acc1[3][r], cst1[r]);
            store_h4(Aw, hoff1, hv);               // h1(i-1) -> c3c4
        }
        if (encX || decX0) {
            if (kk1 == 0) store_prev(Aw, m, pre_f);
            else          Aw[offX(kk1, m)] = f2bf(s_emb[ebase1 + pre_i1 * estr1]);
            if (bx2)      Aw[offX(kk2, m)] = f2bf(s_emb[ebase2 + pre_i2 * 7]);
        }
        __syncthreads();
    }

    // ============ decoder: all waves compute (each owns its c1 quarter) =====
#pragma unroll
    for (int c = 0; c < 3; c++)
#pragma unroll
        for (int g = 0; g < 4; g++) {
            wA0[c][g] = *(const bf16x8*)(wsu + WDF +
                (c * 16 + g * 4 + w) * 512 + l * 8);
            pinv(wA0[c][g]);
        }
#pragma unroll
    for (int g = 0; g < 4; g++) {
        bias0[g] = *(const f32x4*)(wsf + F_BD + g * 64 + u0);
        pinf(bias0[g]);
    }

    for (int t = 0; t < DEC; ++t) {
        const ushort* Ar = Abuf[(t + 1) & 1];
        ushort* Aw = Abuf[t & 1];

        int pre_i1 = 0, pre_i2 = 0;
        const bool dX = (t + 1 < DEC);
        if (dX) {
            if (kk1 >= 1) pre_i1 = decoder_time[((b0g + m) * DEC + (t + 1)) * 4 + sel1];
            if (bx2)      pre_i2 = decoder_time[((b0g + m) * DEC + (t + 1)) * 4 + 3];
        }

        {
            bf16x8 ah[3];
            ah[0] = *(const bf16x8*)(Ar + 0 * 512 + l * 8);   // xin (c0)
            ah[1] = *(const bf16x8*)(Ar + 3 * 512 + l * 8);   // h1 lo (c3)
            ah[2] = *(const bf16x8*)(Ar + 4 * 512 + l * 8);   // h1 hi (c4)
            f32x4 acc[4];
#pragma unroll
            for (int g = 0; g < 4; g++)
                acc[g] = __builtin_amdgcn_mfma_f32_16x16x32_bf16(
                    wA0[0][g], ah[0], bias0[g], 0, 0, 0);
#pragma unroll
            for (int c = 1; c < 3; c++)
#pragma unroll
                for (int g = 0; g < 4; g++)
                    acc[g] = __builtin_amdgcn_mfma_f32_16x16x32_bf16(
                        wA0[c][g], ah[c], acc[g], 0, 0, 0);
            float hv[4];
#pragma unroll
            for (int r = 0; r < 4; r++)
                hv[r] = lstm_cell(acc[0][r], acc[1][r], acc[2][r], acc[3][r], cst1[r]);
            store_h4(Aw, hoff1, hv);                 // h1 recurrent -> c3c4
            *(f32x4*)&sh1[m * 68 + u0] = *(f32x4*)hv;
        }
        if (dX && kk1 >= 1) Aw[offX(kk1, m)] = f2bf(s_emb[ebase1 + pre_i1 * estr1]);
        if (dX && bx2)      Aw[offX(kk2, m)] = f2bf(s_emb[ebase2 + pre_i2 * 7]);
        __syncthreads();

        if (tid < 16) {
            float a = s_bout;
#pragma unroll 16
            for (int u = 0; u < 64; u++) a = fmaf(s_wout[u], sh1[tid * 68 + u], a);
            out[(b0g + tid) * DEC + t] = a;
            if (t + 1 < DEC) store_prev(Aw, tid, a);   // fp32-accurate prev (hi+lo)
        }
        __syncthreads();
    }
}

extern "C" void kernel_launch(void* const* d_in, const int* in_sizes, int n_in,
                              void* d_out, int out_size, void* d_ws, size_t ws_size,
                              hipStream_t stream)
{
    typedef const float* fp;
    const int* input_time   = (const int*)d_in[1];
    fp         label_p      = (fp)d_in[2];
    const int* decoder_time = (const int*)d_in[3];

    prep_kernel<<<128, 256, 0, stream>>>(
        (fp)d_in[4],  (fp)d_in[5],  (fp)d_in[6],  (fp)d_in[7],
        (fp)d_in[8],  (fp)d_in[9],  (fp)d_in[10], (fp)d_in[11],
        (fp)d_in[12], (fp)d_in[13], (fp)d_in[14], (fp)d_in[15],
        (fp)d_in[16], (fp)d_in[17],
        (fp)d_in[18], (fp)d_in[19], (fp)d_in[20], (fp)d_in[21],
        d_ws);

    lstm_mfma<<<NBLK, 256, 0, stream>>>(
        input_time, label_p, decoder_time, d_ws, (float*)d_out);
}

// Round 16
// 284.788 us; speedup vs baseline: 1.2670x; 1.2670x over previous
//
#include <hip/hip_runtime.h>

#define DEVFN __device__ __forceinline__

typedef float  f32x4  __attribute__((ext_vector_type(4)));
typedef short  bf16x8 __attribute__((ext_vector_type(8)));

// Problem constants
constexpr int ENC = 168;
constexpr int DEC = 24;
constexpr int BT  = 16;            // batch tile (MFMA N)
constexpr int NBLK = 4096 / BT;    // 256 blocks -> 1 per CU

constexpr float LOG2E  = 1.4426950408889634f;
constexpr float LOG2E2 = 2.8853900817779268f;

// Workspace layout. ushort region: bf16 weight fragments [c][tt16][lane64][j8]
// K-maps: L0: k<20 x (c0), k==20 dup of col0 (lo-plane), k in[32,96) h0 (c1,c2)
//         L1: k<64 h0 (c1,c2), k in[64,128) h1 (c3,c4)
//         DEC: k<20 xin (c0), k==20 dup col0, k in[32,96) h1 (c3,c4)
constexpr int W0F = 0;             // 3*16*512 = 24576 ushorts
constexpr int W1F = 24576;         // 4*16*512 = 32768
constexpr int WDF = 57344;         // 3*16*512 = 24576
// float region (float indices; ushort total 81920 = 163840 B = 40960 floats)
constexpr int F_B0   = 40960;
constexpr int F_B1   = 41216;
constexpr int F_BD   = 41472;
constexpr int F_WOUT = 41728;
constexpr int F_BOUT = 41792;
constexpr int F_EMB  = 41793;      // [574] hour120 wd24 mo52 woy378
constexpr int NEMB = 574;

DEVFN ushort f2bf(float v) {       // fp32 -> bf16 bits, RNE (scalar path)
    unsigned b = __float_as_uint(v);
    return (ushort)((b + 0x7FFFu + ((b >> 16) & 1u)) >> 16);
}
DEVFN float bf2f(ushort u) { return __uint_as_float(((unsigned)u) << 16); }
DEVFN unsigned cvt_pk_bf16(float a, float b) {  // hw packed RNE
    unsigned r;
    asm("v_cvt_pk_bf16_f32 %0, %1, %2" : "=v"(r) : "v"(a), "v"(b));
    return r;
}
DEVFN float exp2n(float x) {       // 2^(-x), neg as free input modifier
    float r;
    asm("v_exp_f32 %0, -%1" : "=v"(r) : "v"(x));
    return r;
}
// pin a value into registers: asm consumes+redefines it -> no remat of the load
DEVFN void pinv(bf16x8& v) { asm volatile("" : "+v"(v)); }
DEVFN void pinf(f32x4& v)  { asm volatile("" : "+v"(v)); }

// LSTM cell on pre-scaled gates (i,f,o x log2e; g x 2log2e), fused-rcp pairs.
DEVFN float lstm_cell(float gi, float gf, float gg, float go, float& c) {
    float a  = exp2n(fmaxf(gi, -21.f));            // e^-i
    float b  = exp2n(fmaxf(gg, -43.f));            // e^-2g
    float f  = exp2n(gf);                          // e^-f
    float sf = __builtin_amdgcn_rcpf(1.f + f);
    float it = (1.f - b) * __builtin_amdgcn_rcpf(fmaf(a, b, a + b + 1.f));
    c = fmaf(sf, c, it);
    float d  = exp2n(fmaxf(c, -15.f) * LOG2E2);    // e^-2c
    float o  = exp2n(fmaxf(go, -21.f));            // e^-o
    return (1.f - d) * __builtin_amdgcn_rcpf(fmaf(o, d, o + d + 1.f));
}

// ---------------- prep: weights -> bf16 MFMA fragments (pre-scaled) --------
__global__ void prep_kernel(
    const float* __restrict__ w0ih, const float* __restrict__ w0hh,
    const float* __restrict__ b0ih, const float* __restrict__ b0hh,
    const float* __restrict__ w1ih, const float* __restrict__ w1hh,
    const float* __restrict__ b1ih, const float* __restrict__ b1hh,
    const float* __restrict__ wdih, const float* __restrict__ wdhh,
    const float* __restrict__ bdih, const float* __restrict__ bdhh,
    const float* __restrict__ wout, const float* __restrict__ boutp,
    const float* __restrict__ eh,   const float* __restrict__ ewd,
    const float* __restrict__ emo,  const float* __restrict__ ewoy,
    void* __restrict__ ws)
{
    ushort* wsu = (ushort*)ws;
    float*  wsf = (float*)ws;
    const int total = 81920 + 1407;
    for (int idx = blockIdx.x * blockDim.x + threadIdx.x; idx < total;
         idx += gridDim.x * blockDim.x) {
        if (idx < 81920) {
            int layer, q;
            if (idx < W1F)      { layer = 0; q = idx; }
            else if (idx < WDF) { layer = 1; q = idx - W1F; }
            else                { layer = 2; q = idx - WDF; }
            int c  = q >> 13;
            int tt = (q >> 9) & 15;
            int l  = (q >> 3) & 63;
            int j  = q & 7;
            int k  = c * 32 + (l >> 4) * 8 + j;
            int n  = tt * 16 + (l & 15);
            float v = 0.f;
            if (layer == 0) {
                if (k < 20) v = w0ih[n * 20 + k];
                else if (k == 20) v = w0ih[n * 20];            // lo-plane dup of col0
                else if (k >= 32 && k < 96) v = w0hh[n * 64 + (k - 32)];
            } else if (layer == 1) {
                if (k < 64) v = w1ih[n * 64 + k];
                else        v = w1hh[n * 64 + (k - 64)];
            } else {
                if (k < 20) v = wdih[n * 20 + k];
                else if (k == 20) v = wdih[n * 20];            // lo-plane dup of col0
                else if (k >= 32 && k < 96) v = wdhh[n * 64 + (k - 32)];
            }
            v *= ((n >> 6) == 2) ? LOG2E2 : LOG2E;   // pre-scale for exp2
            wsu[idx] = f2bf(v);
        } else {
            int f = idx - 81920;
            float v;
            if (f < 768) {
                float sc = (((f & 255) >> 6) == 2) ? LOG2E2 : LOG2E;
                if (f < 256)      v = (b0ih[f] + b0hh[f]) * sc;
                else if (f < 512) v = (b1ih[f - 256] + b1hh[f - 256]) * sc;
                else              v = (bdih[f - 512] + bdhh[f - 512]) * sc;
            }
            else if (f < 832) v = wout[f - 768];
            else if (f == 832) v = boutp[0];
            else {
                int e = f - 833;
                if (e < 120)      v = eh[e];
                else if (e < 144) v = ewd[e - 120];
                else if (e < 196) v = emo[e - 144];
                else              v = ewoy[e - 196];
            }
            wsf[40960 + f] = v;
        }
    }
}

DEVFN int offX(int k, int m) {     // chunk0 fragment offset, k in [0,32)
    return (m + 16 * (k >> 3)) * 8 + (k & 7);
}
// packed: 4 consecutive-k h values -> one b64 write
DEVFN void store_h4(ushort* A, int off, const float* h) {
    unsigned h01 = cvt_pk_bf16(h[0], h[1]);
    unsigned h23 = cvt_pk_bf16(h[2], h[3]);
    asm volatile("" : "+v"(h01), "+v"(h23));
    unsigned long long p = ((unsigned long long)h23 << 32) | h01;
    *(unsigned long long*)(A + off) = p;
}
// hi/lo pair for the k=0 feature (label/prev): hi at k=0, lo at k=20
DEVFN void store_prev(ushort* A, int m, float v) {
    ushort hi = f2bf(v);
    A[offX(0, m)]  = hi;
    A[offX(20, m)] = f2bf(v - bf2f(hi));
}

// ---------------- main persistent MFMA kernel: 512 thr ---------------------
// Waves 0-3: layer0 (encoder) + x-build. Waves 4-7: layer1 (enc) then decoder.
// Wave wl computes gate tiles {gamma*4+wl}: lane (q,m) owns all 4 gates of
// units u0..u0+3 (u0=wl*16+q*4) for batch m -> lane-local cell update.
__global__ __launch_bounds__(512)
__attribute__((amdgpu_waves_per_eu(2, 2)))
void lstm_mfma(
    const int* __restrict__ input_time, const float* __restrict__ label_p,
    const int* __restrict__ decoder_time, const void* __restrict__ ws,
    float* __restrict__ out)
{
    const ushort* wsu = (const ushort*)ws;
    const float*  wsf = (const float*)ws;

    // double-buffered activations: c0=x/xin, c1c2=h0, c3c4=h1 (bf16 frags)
    __shared__ __align__(16) ushort Abuf[2][5 * 512];
    __shared__ float s_emb[NEMB];
    __shared__ float s_wout[64];
    __shared__ float sh1[16 * 68];     // [m][u] padded
    __shared__ float s_bout;

    const int tid = threadIdx.x;
    const int w   = tid >> 6;          // wave 0..7
    const int l   = tid & 63;
    const int q   = l >> 4;
    const int m   = l & 15;
    const int wl  = w & 3;
    const bool isL0 = (w < 4);
    const int b0g = blockIdx.x * BT;
    const int u0  = wl * 16 + q * 4;   // this lane's 4 units

    // h fragment store offset: L0 -> c1c2 (base), L1/dec -> c3c4 (+1024)
    const int hoff = (1 + (u0 >> 5)) * 512 +
                     (m + 16 * ((u0 & 31) >> 3)) * 8 + (u0 & 7) +
                     (isL0 ? 0 : 1024);

    // ---- init ----
    for (int i = tid; i < 2 * 5 * 512; i += 512) ((ushort*)Abuf)[i] = 0;
    for (int i = tid; i < NEMB; i += 512) s_emb[i] = wsf[F_EMB + i];
    if (tid < 64) s_wout[tid] = wsf[F_WOUT + tid];
    if (tid == 0) s_bout = wsf[F_BOUT];

    // ---- weight fragments (A-operand, bf16), pinned register-resident ----
    bf16x8 wA[4][4];                   // [chunk][gamma]; L0/dec use [0..2][*]
    if (isL0) {
#pragma unroll
        for (int c = 0; c < 3; c++)
#pragma unroll
            for (int g = 0; g < 4; g++)
                wA[c][g] = *(const bf16x8*)(wsu + W0F +
                    (c * 16 + g * 4 + wl) * 512 + l * 8);
        wA[3][0] = wA[3][1] = wA[3][2] = wA[3][3] = bf16x8{0,0,0,0,0,0,0,0};
    } else {
#pragma unroll
        for (int c = 0; c < 4; c++)
#pragma unroll
            for (int g = 0; g < 4; g++)
                wA[c][g] = *(const bf16x8*)(wsu + W1F +
                    (c * 16 + g * 4 + wl) * 512 + l * 8);
    }
#pragma unroll
    for (int c = 0; c < 4; c++)
#pragma unroll
        for (int g = 0; g < 4; g++) pinv(wA[c][g]);

    f32x4 biasv[4];
#pragma unroll
    for (int g = 0; g < 4; g++) {
        biasv[g] = *(const f32x4*)(wsf + (isL0 ? F_B0 : F_B1) + g * 64 + u0);
        pinf(biasv[g]);
    }

    float cst[4] = {0.f, 0.f, 0.f, 0.f};

    // x-build roles (L0 waves only): primary kk1 = tid>>4 (0..15);
    // secondary kk2 = kk1+16 (16..19) for tid<64. batch = tid&15 = m.
    const int kk1 = tid >> 4;
    const int kk2 = kk1 + 16;
    const bool bx2 = (tid < 64);
    // hoisted emb addressing: lookup = s_emb[ebase + idx*estr]
    int sel1 = 0, estr1 = 0, ebase1 = 0;
    if (kk1 >= 1) {
        int f = kk1 - 1;
        if (f < 5)       { sel1 = 0; estr1 = 5; ebase1 = 0   + f; }
        else if (f < 8)  { sel1 = 1; estr1 = 3; ebase1 = 120 + (f - 5); }
        else if (f < 12) { sel1 = 2; estr1 = 4; ebase1 = 144 + (f - 8); }
        else             { sel1 = 3; estr1 = 7; ebase1 = 196 + (f - 12); }
    }
    const int ebase2 = 196 + (kk2 - 13);   // woy table, stride 7

    __syncthreads();
    if (isL0) {    // x(0) into Abuf[0]
        if (kk1 == 0) {
            store_prev(Abuf[0], m, label_p[(b0g + m) * ENC]);
        } else {
            int idx = input_time[((b0g + m) * ENC) * 4 + sel1];
            Abuf[0][offX(kk1, m)] = f2bf(s_emb[ebase1 + idx * estr1]);
        }
        if (bx2) {
            int idx2 = input_time[((b0g + m) * ENC) * 4 + 3];
            Abuf[0][offX(kk2, m)] = f2bf(s_emb[ebase2 + idx2 * 7]);
        }
    }
    __syncthreads();

    // ============ encoder pipeline: iter i = layer0(i) + layer1(i-1) ========
    for (int i = 0; i <= ENC; ++i) {
        const ushort* Ar = Abuf[i & 1];
        ushort* Aw = Abuf[(i + 1) & 1];
        const bool active = isL0 ? (i < ENC) : (i >= 1);

        // prefetch globals for next x (L0 waves)
        float pre_f = 0.f; int pre_i1 = 0, pre_i2 = 0;
        const bool encX  = (i + 1 < ENC) && isL0;
        const bool decX0 = (i == ENC) && isL0;
        if (encX) {
            if (kk1 == 0) pre_f  = label_p[(b0g + m) * ENC + (i + 1)];
            else          pre_i1 = input_time[((b0g + m) * ENC + (i + 1)) * 4 + sel1];
            if (bx2)      pre_i2 = input_time[((b0g + m) * ENC + (i + 1)) * 4 + 3];
        } else if (decX0) {
            if (kk1 == 0) pre_f  = label_p[(b0g + m) * ENC + (ENC - 1)];
            else          pre_i1 = decoder_time[((b0g + m) * DEC) * 4 + sel1];
            if (bx2)      pre_i2 = decoder_time[((b0g + m) * DEC) * 4 + 3];
        }

        if (active) {
            f32x4 acc[4];
            if (isL0) {
                bf16x8 ah[3];
#pragma unroll
                for (int c = 0; c < 3; c++)
                    ah[c] = *(const bf16x8*)(Ar + c * 512 + l * 8);
#pragma unroll
                for (int g = 0; g < 4; g++)
                    acc[g] = __builtin_amdgcn_mfma_f32_16x16x32_bf16(
                        wA[0][g], ah[0], biasv[g], 0, 0, 0);
#pragma unroll
                for (int c = 1; c < 3; c++)
#pragma unroll
                    for (int g = 0; g < 4; g++)
                        acc[g] = __builtin_amdgcn_mfma_f32_16x16x32_bf16(
                            wA[c][g], ah[c], acc[g], 0, 0, 0);
            } else {
                bf16x8 ah[4];
#pragma unroll
                for (int c = 0; c < 4; c++)
                    ah[c] = *(const bf16x8*)(Ar + (1 + c) * 512 + l * 8);
#pragma unroll
                for (int g = 0; g < 4; g++)
                    acc[g] = __builtin_amdgcn_mfma_f32_16x16x32_bf16(
                        wA[0][g], ah[0], biasv[g], 0, 0, 0);
#pragma unroll
                for (int c = 1; c < 4; c++)
#pragma unroll
                    for (int g = 0; g < 4; g++)
                        acc[g] = __builtin_amdgcn_mfma_f32_16x16x32_bf16(
                            wA[c][g], ah[c], acc[g], 0, 0, 0);
            }
            float hv[4];
#pragma unroll
            for (int r = 0; r < 4; r++)
                hv[r] = lstm_cell(acc[0][r], acc[1][r], acc[2][r], acc[3][r], cst[r]);
            store_h4(Aw, hoff, hv);    // single store: h0->c1c2 or h1->c3c4
        }
        if (encX || decX0) {
            if (kk1 == 0) store_prev(Aw, m, pre_f);
            else          Aw[offX(kk1, m)] = f2bf(s_emb[ebase1 + pre_i1 * estr1]);
            if (bx2)      Aw[offX(kk2, m)] = f2bf(s_emb[ebase2 + pre_i2 * 7]);
        }
        __syncthreads();
    }

    // ============ decoder: waves 4-7 compute (own c1); L0 waves build x =====
    if (!isL0) {
#pragma unroll
        for (int c = 0; c < 3; c++)
#pragma unroll
            for (int g = 0; g < 4; g++)
                wA[c][g] = *(const bf16x8*)(wsu + WDF +
                    (c * 16 + g * 4 + wl) * 512 + l * 8);
#pragma unroll
        for (int c = 0; c < 3; c++)
#pragma unroll
            for (int g = 0; g < 4; g++) pinv(wA[c][g]);
#pragma unroll
        for (int g = 0; g < 4; g++) {
            biasv[g] = *(const f32x4*)(wsf + F_BD + g * 64 + u0);
            pinf(biasv[g]);
        }
    }

    for (int t = 0; t < DEC; ++t) {
        const ushort* Ar = Abuf[(t + 1) & 1];
        ushort* Aw = Abuf[t & 1];

        int pre_i1 = 0, pre_i2 = 0;
        const bool dX = (t + 1 < DEC) && isL0;
        if (dX) {
            if (kk1 >= 1) pre_i1 = decoder_time[((b0g + m) * DEC + (t + 1)) * 4 + sel1];
            if (bx2)      pre_i2 = decoder_time[((b0g + m) * DEC + (t + 1)) * 4 + 3];
        }

        if (!isL0) {
            bf16x8 ah[3];
            ah[0] = *(const bf16x8*)(Ar + 0 * 512 + l * 8);   // xin (c0)
            ah[1] = *(const bf16x8*)(Ar + 3 * 512 + l * 8);   // h1 lo (c3)
            ah[2] = *(const bf16x8*)(Ar + 4 * 512 + l * 8);   // h1 hi (c4)
            f32x4 acc[4];
#pragma unroll
            for (int g = 0; g < 4; g++)
                acc[g] = __builtin_amdgcn_mfma_f32_16x16x32_bf16(
                    wA[0][g], ah[0], biasv[g], 0, 0, 0);
#pragma unroll
            for (int c = 1; c < 3; c++)
#pragma unroll
                for (int g = 0; g < 4; g++)
                    acc[g] = __builtin_amdgcn_mfma_f32_16x16x32_bf16(
                        wA[c][g], ah[c], acc[g], 0, 0, 0);
            float hv[4];
#pragma unroll
            for (int r = 0; r < 4; r++)
                hv[r] = lstm_cell(acc[0][r], acc[1][r], acc[2][r], acc[3][r], cst[r]);
            store_h4(Aw, hoff, hv);                 // h1 recurrent -> c3c4
            *(f32x4*)&sh1[m * 68 + u0] = *(f32x4*)hv;
        }
        if (dX && kk1 >= 1) Aw[offX(kk1, m)] = f2bf(s_emb[ebase1 + pre_i1 * estr1]);
        if (dX && bx2)      Aw[offX(kk2, m)] = f2bf(s_emb[ebase2 + pre_i2 * 7]);
        __syncthreads();

        if (tid < 16) {
            float a = s_bout;
#pragma unroll 16
            for (int u = 0; u < 64; u++) a = fmaf(s_wout[u], sh1[tid * 68 + u], a);
            out[(b0g + tid) * DEC + t] = a;
            if (t + 1 < DEC) store_prev(Aw, tid, a);   // fp32-accurate prev (hi+lo)
        }
        __syncthreads();
    }
}

extern "C" void kernel_launch(void* const* d_in, const int* in_sizes, int n_in,
                              void* d_out, int out_size, void* d_ws, size_t ws_size,
                              hipStream_t stream)
{
    typedef const float* fp;
    const int* input_time   = (const int*)d_in[1];
    fp         label_p      = (fp)d_in[2];
    const int* decoder_time = (const int*)d_in[3];

    prep_kernel<<<128, 256, 0, stream>>>(
        (fp)d_in[4],  (fp)d_in[5],  (fp)d_in[6],  (fp)d_in[7],
        (fp)d_in[8],  (fp)d_in[9],  (fp)d_in[10], (fp)d_in[11],
        (fp)d_in[12], (fp)d_in[13], (fp)d_in[14], (fp)d_in[15],
        (fp)d_in[16], (fp)d_in[17],
        (fp)d_in[18], (fp)d_in[19], (fp)d_in[20], (fp)d_in[21],
        d_ws);

    lstm_mfma<<<NBLK, 512, 0, stream>>>(
        input_time, label_p, decoder_time, d_ws, (float*)d_out);
}